// Round 2
// baseline (221.349 us; speedup 1.0000x reference)
//
#include <hip/hip_runtime.h>
#include <math.h>

// GCN 2-layer, N=100000, E=3200000, feats 2->16->2.
// R9: fine partition level DELETED. Aggregation runs directly on the 49 coarse
// buckets (2048 nodes = 16KB SoA LDS accumulators per block), one block per
// (coarse bucket, 8192-edge chunk), writing non-atomic coalesced 16KB partials;
// a per-node combine kernel sums the <=9 chunk partials and applies
// dinv / fused MLP / log_softmax. Degree uses the same chunk-partial scheme.
// Removes: k_pass2 fine scatter (3.2M LDS cursor atomics + 3.2M scattered
// stores + 16MB slotsF write + 25.6MB slotsF re-reads) and the 1563 tiny
// latency-bound fine-bucket blocks (old agg: HBM 3%, VALU 2% = pure stall).
// LDS atomic contention drops too: 8192 edges into 2048 bins (~4/bin) vs 64.
//
// Pipeline: k_pass1 (edges -> 49 coarse, packed (src<<11|dstLocal))
//           k_deg   (chunk -> 2048-bin LDS hist -> degPart[441][2048])
//           k_dinv  (sum nch partials -> dinv, sx = x*dinv)
//           k_aggc  (chunk -> gather sx[src] -> LDS acc[2048] -> partX/partY)
//           k_comb1 (sum partials + self, *di, fused MLP -> sz)
//           k_aggc  (same over sz, reusing partX/partY)
//           k_comb2 (sum + bias + log_softmax -> out)

constexpr int N = 100000;
constexpr int NC = 49;          // coarse buckets (dst>>11)
constexpr int CB = 2048;        // nodes per coarse bucket
constexpr int CAP1 = 68608;     // coarse cap: mean 65536 + ~12 sigma
constexpr int BSP = 512;
constexpr int ECHUNK = 8192;
constexpr int EPT = ECHUNK / BSP;  // 16 edges/thread, in registers
constexpr int MAXCH = 9;           // chunks per coarse region (9*8192 >= CAP1)

__global__ __launch_bounds__(BSP) void k_pass1(const int* __restrict__ src,
                                               const int* __restrict__ dst, int E,
                                               int* __restrict__ gfill1,
                                               int* __restrict__ slotsC) {
    __shared__ int hist[NC];
    __shared__ int base[NC];
    int t = threadIdx.x;
    if (t < NC) hist[t] = 0;
    __syncthreads();
    int s[EPT], d[EPT];
    int ebase = blockIdx.x * ECHUNK + t * EPT;
#pragma unroll
    for (int k = 0; k < EPT / 4; k++) {
        int idx = ebase + 4 * k;
        if (idx + 3 < E) {
            *(int4*)(s + 4 * k) = *(const int4*)(src + idx);
            *(int4*)(d + 4 * k) = *(const int4*)(dst + idx);
        } else {
            for (int j = 0; j < 4; j++) {
                s[4 * k + j] = (idx + j < E) ? src[idx + j] : -1;
                d[4 * k + j] = (idx + j < E) ? dst[idx + j] : -1;
            }
        }
    }
#pragma unroll
    for (int k = 0; k < EPT; k++)
        if (d[k] >= 0) atomicAdd(&hist[d[k] >> 11], 1);
    __syncthreads();
    if (t < NC) {
        int c = hist[t];
        base[t] = c ? atomicAdd(&gfill1[t], c) : 0;  // device reservation atomic
        hist[t] = 0;                                  // reuse as cursor
    }
    __syncthreads();
#pragma unroll
    for (int k = 0; k < EPT; k++) {
        if (d[k] >= 0) {
            int bin = d[k] >> 11;
            int r = atomicAdd(&hist[bin], 1);  // LDS
            int pos = base[bin] + r;
            if (pos < CAP1) slotsC[bin * CAP1 + pos] = (s[k] << 11) | (d[k] & 2047);
        }
    }
}

// per-(bucket,chunk) degree histogram -> degPart[block][2048], non-atomic store
__global__ __launch_bounds__(BSP) void k_deg(const int* __restrict__ gfill1,
                                             const int* __restrict__ slotsC,
                                             int* __restrict__ degPart) {
    __shared__ int dh[CB];
    int c = blockIdx.x / MAXCH, j = blockIdx.x % MAXCH;
    int fill = min(gfill1[c], CAP1);
    int e0 = j * ECHUNK;
    if (e0 >= fill) return;  // uniform per block, before any sync
    int e1 = min(fill, e0 + ECHUNK);
    int t = threadIdx.x;
    for (int i = t; i < CB; i += BSP) dh[i] = 0;
    __syncthreads();
    const int* row = slotsC + c * CAP1;
    int v[EPT];
    int ebase = e0 + t * EPT;
#pragma unroll
    for (int k = 0; k < EPT / 4; k++) {
        int idx = ebase + 4 * k;
        if (idx + 3 < e1) {
            *(int4*)(v + 4 * k) = *(const int4*)(row + idx);
        } else {
            for (int jj = 0; jj < 4; jj++) v[4 * k + jj] = (idx + jj < e1) ? row[idx + jj] : -1;
        }
    }
#pragma unroll
    for (int k = 0; k < EPT; k++)
        if (v[k] >= 0) atomicAdd(&dh[v[k] & (CB - 1)], 1);
    __syncthreads();
    int* dp = degPart + blockIdx.x * CB;
    for (int i = t; i < CB; i += BSP) dp[i] = dh[i];
}

// per node: deg = sum of nch chunk partials; dinv = rsqrt(deg+1); sx = x*dinv
__global__ __launch_bounds__(256) void k_dinv(const int* __restrict__ gfill1,
                                              const int* __restrict__ degPart,
                                              const float* __restrict__ x,
                                              float* __restrict__ dinv,
                                              float2* __restrict__ sx) {
    int node = blockIdx.x * 256 + threadIdx.x;
    if (node >= N) return;
    int c = node >> 11, i = node & (CB - 1);
    int nch = (min(gfill1[c], CAP1) + ECHUNK - 1) / ECHUNK;
    const int* p = degPart + c * MAXCH * CB + i;
    int deg = 0;
    for (int j = 0; j < nch; j++) deg += p[j * CB];
    float di = rsqrtf((float)(deg + 1));
    dinv[node] = di;
    float2 xv = ((const float2*)x)[node];
    sx[node] = make_float2(xv.x * di, xv.y * di);
}

// per-(bucket,chunk) aggregate: gather vals[src], LDS acc over 2048 local dst,
// write coalesced non-atomic partials.
__global__ __launch_bounds__(BSP) void k_aggc(const int* __restrict__ gfill1,
                                              const int* __restrict__ slotsC,
                                              const float2* __restrict__ vals,
                                              float* __restrict__ partX,
                                              float* __restrict__ partY) {
    __shared__ float aX[CB], aY[CB];
    int c = blockIdx.x / MAXCH, j = blockIdx.x % MAXCH;
    int fill = min(gfill1[c], CAP1);
    int e0 = j * ECHUNK;
    if (e0 >= fill) return;  // uniform per block, before any sync
    int e1 = min(fill, e0 + ECHUNK);
    int t = threadIdx.x;
    for (int i = t; i < CB; i += BSP) { aX[i] = 0.f; aY[i] = 0.f; }
    __syncthreads();
    const int* row = slotsC + c * CAP1;
    int v[EPT];
    int ebase = e0 + t * EPT;
#pragma unroll
    for (int k = 0; k < EPT / 4; k++) {
        int idx = ebase + 4 * k;
        if (idx + 3 < e1) {
            *(int4*)(v + 4 * k) = *(const int4*)(row + idx);
        } else {
            for (int jj = 0; jj < 4; jj++) v[4 * k + jj] = (idx + jj < e1) ? row[idx + jj] : -1;
        }
    }
    // 16 independent gathers issued before any atomic (deep MLP pipelining)
    float2 g[EPT];
#pragma unroll
    for (int k = 0; k < EPT; k++) g[k] = (v[k] >= 0) ? vals[v[k] >> 11] : make_float2(0.f, 0.f);
#pragma unroll
    for (int k = 0; k < EPT; k++) {
        if (v[k] >= 0) {
            int d = v[k] & (CB - 1);
            atomicAdd(&aX[d], g[k].x);
            atomicAdd(&aY[d], g[k].y);
        }
    }
    __syncthreads();
    float* px = partX + blockIdx.x * CB;
    float* py = partY + blockIdx.x * CB;
    for (int i = t; i < CB; i += BSP) { px[i] = aX[i]; py[i] = aY[i]; }
}

// combine layer1 partials + self, *di, fused MLP; sz = (h@W2)*di
__global__ __launch_bounds__(256) void k_comb1(const int* __restrict__ gfill1,
                                               const float* __restrict__ partX,
                                               const float* __restrict__ partY,
                                               const float* __restrict__ dinv,
                                               const float2* __restrict__ sx,
                                               const float* __restrict__ W1,
                                               const float* __restrict__ b1,
                                               const float* __restrict__ W2,
                                               float2* __restrict__ sz) {
    __shared__ float sW1[32], sb1[16], sW2[32];
    int t = threadIdx.x;
    if (t < 32) sW1[t] = W1[t];
    else if (t < 48) sb1[t - 32] = b1[t - 32];
    else if (t < 80) sW2[t - 48] = W2[t - 48];
    __syncthreads();
    int node = blockIdx.x * 256 + t;
    if (node >= N) return;
    int c = node >> 11, i = node & (CB - 1);
    int nch = (min(gfill1[c], CAP1) + ECHUNK - 1) / ECHUNK;
    const float* px = partX + c * MAXCH * CB + i;
    const float* py = partY + c * MAXCH * CB + i;
    float ax = 0.f, ay = 0.f;
    for (int j = 0; j < nch; j++) { ax += px[j * CB]; ay += py[j * CB]; }
    float di = dinv[node];
    float2 sv = sx[node];
    float a0 = (ax + sv.x) * di;
    float a1 = (ay + sv.y) * di;
    float z0 = 0.f, z1 = 0.f;
#pragma unroll
    for (int k = 0; k < 16; k++) {
        float h = fmaf(a0, sW1[k], fmaf(a1, sW1[16 + k], sb1[k]));
        h = fmaxf(h, 0.f);
        z0 = fmaf(h, sW2[2 * k + 0], z0);
        z1 = fmaf(h, sW2[2 * k + 1], z1);
    }
    sz[node] = make_float2(z0 * di, z1 * di);
}

// combine layer2 partials + self, *di, + bias, log_softmax
__global__ __launch_bounds__(256) void k_comb2(const int* __restrict__ gfill1,
                                               const float* __restrict__ partX,
                                               const float* __restrict__ partY,
                                               const float* __restrict__ dinv,
                                               const float2* __restrict__ sz,
                                               const float* __restrict__ b2,
                                               float2* __restrict__ out) {
    int node = blockIdx.x * 256 + threadIdx.x;
    if (node >= N) return;
    int c = node >> 11, i = node & (CB - 1);
    int nch = (min(gfill1[c], CAP1) + ECHUNK - 1) / ECHUNK;
    const float* px = partX + c * MAXCH * CB + i;
    const float* py = partY + c * MAXCH * CB + i;
    float ax = 0.f, ay = 0.f;
    for (int j = 0; j < nch; j++) { ax += px[j * CB]; ay += py[j * CB]; }
    float di = dinv[node];
    float2 sv = sz[node];
    float v0 = fmaf(ax + sv.x, di, b2[0]);
    float v1 = fmaf(ay + sv.y, di, b2[1]);
    float m = fmaxf(v0, v1);
    float lse = m + logf(expf(v0 - m) + expf(v1 - m));
    out[node] = make_float2(v0 - lse, v1 - lse);
}

extern "C" void kernel_launch(void* const* d_in, const int* in_sizes, int n_in,
                              void* d_out, int out_size, void* d_ws, size_t ws_size,
                              hipStream_t stream) {
    const float* x  = (const float*)d_in[0];
    const int*   ei = (const int*)d_in[1];
    const float* W1 = (const float*)d_in[2];
    const float* b1 = (const float*)d_in[3];
    const float* W2 = (const float*)d_in[4];
    const float* b2 = (const float*)d_in[5];

    const int E = in_sizes[1] / 2;
    const int* src = ei;
    const int* dst = ei + E;
    const int GP = (E + ECHUNK - 1) / ECHUNK;  // 391
    const int GB = NC * MAXCH;                 // 441 chunk blocks
    const int GN = (N + 255) / 256;            // 391 node blocks

    char* ws = (char*)d_ws;
    size_t off = 0;
    auto alloc = [&](size_t bytes) {
        char* p = ws + off;
        off += (bytes + 511) & ~size_t(511);
        return p;
    };
    int*    gfill1  = (int*)alloc(NC * sizeof(int));
    float*  dinv    = (float*)alloc(N * sizeof(float));
    float2* sx      = (float2*)alloc(N * sizeof(float2));
    float2* sz      = (float2*)alloc(N * sizeof(float2));
    int*    slotsC  = (int*)alloc((size_t)NC * CAP1 * sizeof(int));      // 13.4 MB
    int*    degPart = (int*)alloc((size_t)GB * CB * sizeof(int));        // 3.6 MB
    float*  partX   = (float*)alloc((size_t)GB * CB * sizeof(float));    // 3.6 MB
    float*  partY   = (float*)alloc((size_t)GB * CB * sizeof(float));    // 3.6 MB

    hipMemsetAsync(gfill1, 0, NC * sizeof(int), stream);

    k_pass1<<<GP, BSP, 0, stream>>>(src, dst, E, gfill1, slotsC);
    k_deg<<<GB, BSP, 0, stream>>>(gfill1, slotsC, degPart);
    k_dinv<<<GN, 256, 0, stream>>>(gfill1, degPart, x, dinv, sx);
    k_aggc<<<GB, BSP, 0, stream>>>(gfill1, slotsC, sx, partX, partY);
    k_comb1<<<GN, 256, 0, stream>>>(gfill1, partX, partY, dinv, sx, W1, b1, W2, sz);
    k_aggc<<<GB, BSP, 0, stream>>>(gfill1, slotsC, sz, partX, partY);
    k_comb2<<<GN, 256, 0, stream>>>(gfill1, partX, partY, dinv, sz, b2, (float2*)d_out);
}